// Round 3
// baseline (1530.183 us; speedup 1.0000x reference)
//
#include <hip/hip_runtime.h>
#include <math.h>

#define BB 16
#define TT 500
#define CC 2048
#define SN 64
#define SD 512
#define NGRP 16
#define NDENWG 64       // 8 pairs x 8 column blocks; bid = cb*8 + gp
                        // => bid%8 == gp: all 8 WGs of a pair on ONE XCD
#define NTHR 512
#define SHIFTC 30.0f

// ws layout:
//   bytes [0, 131072): u64 pg[2][16][512] -- (tag<<32)|float_bits, [slot][group][state]
//   float index 32768+: DACC[16], DSCALE[16], NACC[16], NSCALE[16]
#define WSF_DACC   32768
#define WSF_DSCALE 32784
#define WSF_NACC   32800
#define WSF_NSCALE 32816

#define AL(p) __hip_atomic_load((p), __ATOMIC_RELAXED, __HIP_MEMORY_SCOPE_AGENT)
#define AS(p, v) __hip_atomic_store((p), (v), __ATOMIC_RELAXED, __HIP_MEMORY_SCOPE_AGENT)

typedef float f4 __attribute__((ext_vector_type(4)));

__device__ __forceinline__ float wave_max(float v) {
  #pragma unroll
  for (int off = 32; off > 0; off >>= 1) v = fmaxf(v, __shfl_xor(v, off, 64));
  return v;
}
__device__ __forceinline__ float wave_sum(float v) {
  #pragma unroll
  for (int off = 32; off > 0; off >>= 1) v += __shfl_xor(v, off, 64);
  return v;
}
__device__ __forceinline__ unsigned long long pk(unsigned tag, float v) {
  return ((unsigned long long)tag << 32) | (unsigned long long)__float_as_uint(v);
}
__device__ __forceinline__ float clamp30(float v) {
  return fminf(fmaxf(v, -30.f), 30.f);
}
__device__ __forceinline__ float rlane(float v, int k) {
  return __uint_as_float(__builtin_amdgcn_readlane(__float_as_uint(v), k));
}
// record holding tag T for group g lives at slot (T&1)
__device__ __forceinline__ unsigned long long* recbase(
    unsigned long long* p64, int g, int tag) {
  return p64 + ((tag & 1) ? (size_t)(NGRP + g) : (size_t)g) * SD;
}

__global__ __launch_bounds__(NTHR, 1) void fsm_fwd(
    const float* __restrict__ x, const int* __restrict__ seqlens,
    const float* __restrict__ nA, const float* __restrict__ nls,
    const float* __restrict__ nlf, const int* __restrict__ npdf,
    const float* __restrict__ dA, const float* __restrict__ dls,
    const float* __restrict__ dlf, const int* __restrict__ dpdf,
    unsigned long long* __restrict__ p64, float* __restrict__ wsf)
{
  __shared__ float prt[2][2][8][64];   // [phase][t-parity][wave][lane]
  __shared__ float pmx[2][2][8];
  const int tid = threadIdx.x;
  const int lane = tid & 63, wv = tid >> 6;

  if (blockIdx.x < NDENWG) {
    // ---- DEN: 2 groups (gp, gp+8) pipelined through one XCD-local WG set ---
    const int gp = blockIdx.x & 7;      // pair id == XCD id (bid%8)
    const int cb = blockIdx.x >> 3;     // column block (0..7)
    const int j0 = cb * 64;
    const int g0 = gp, g1 = gp + 8;

    // A in registers: shared by both groups (den A is batch-independent)
    f4 Areg[16];
    {
      const float* Ap = dA + (wv * 64) * SD + j0 + lane;
      #pragma unroll
      for (int k = 0; k < 64; ++k)
        Areg[k >> 2][k & 3] = __expf(Ap[k * SD]);
      #pragma unroll
      for (int r = 0; r < 16; ++r)
        asm volatile("" : "+v"(Areg[r]));
    }

    // wave 0 owns the epilogue state for this WG's 64 columns, both groups
    int pdfj = 0, sl0 = 0, sl1 = 0;
    float lfj = 0.f, pc0 = 0.f, pc1 = 0.f, sc0 = SHIFTC, sc1 = SHIFTC;
    if (wv == 0) {
      pdfj = dpdf[j0 + lane];
      lfj  = dlf[j0 + lane];
      sl0  = seqlens[g0];
      sl1  = seqlens[g1];
      float ls = dls[j0 + lane];
      pc0 = __expf(ls + clamp30(x[g0 * (TT * CC) + pdfj]) - SHIFTC);
      pc1 = __expf(ls + clamp30(x[g1 * (TT * CC) + pdfj]) - SHIFTC);
      AS(recbase(p64, g0, 0) + j0 + lane, pk(0u, pc0));
      AS(recbase(p64, g1, 0) + j0 + lane, pk(0u, pc1));
    }
    // prefetch first poll (g0, tag 0) and first emission (g0, t=1)
    unsigned long long pf = AL(recbase(p64, g0, 0) + wv * 64 + lane);
    float xvp = 0.f, xvn = 0.f;
    if (wv == 0) xvp = clamp30(x[g0 * (TT * CC) + CC + pdfj]);

    for (int t = 1; t < TT; ++t) {
      const unsigned tg = (unsigned)(t - 1);

      // ================= phase 0 : group g0 =================
      {
        unsigned long long* pa = recbase(p64, g0, t - 1) + wv * 64 + lane;
        unsigned long long w = pf;
        while ((unsigned)(w >> 32) != tg) {       // prefetched reg usually hits
          w = AL(pa);
          if ((unsigned)(w >> 32) == tg) break;
          __builtin_amdgcn_s_sleep(1);
        }
        float pv = __uint_as_float((unsigned)w);
        float cm = wave_max(pv);
        if (lane == 0) pmx[0][t & 1][wv] = cm;
        float q = 0.f;
        #pragma unroll
        for (int k = 0; k < 64; ++k)
          q = fmaf(rlane(pv, k), Areg[k >> 2][k & 3], q);
        prt[0][t & 1][wv][lane] = q;
        // issue phase-1 prefetches before the barrier (hide L2 RT)
        pf = AL(recbase(p64, g1, t - 1) + wv * 64 + lane);
        if (wv == 0) xvn = clamp30(x[g1 * (TT * CC) + t * CC + pdfj]);
        __syncthreads();
        if (wv == 0) {
          float qq = 0.f;
          #pragma unroll
          for (int w8 = 0; w8 < 8; ++w8) qq += prt[0][t & 1][w8][lane];
          float m = pmx[0][t & 1][0];
          #pragma unroll
          for (int w8 = 1; w8 < 8; ++w8) m = fmaxf(m, pmx[0][t & 1][w8]);
          float lm = __logf(m);
          if (t < sl0) {
            pc0 = qq * __expf(xvp - SHIFTC - lm);
            sc0 += SHIFTC + lm;
          }
          AS(recbase(p64, g0, t) + j0 + lane, pk((unsigned)t, pc0));
          xvp = xvn;
        }
      }

      // ================= phase 1 : group g1 =================
      {
        unsigned long long* pa = recbase(p64, g1, t - 1) + wv * 64 + lane;
        unsigned long long w = pf;
        while ((unsigned)(w >> 32) != tg) {
          w = AL(pa);
          if ((unsigned)(w >> 32) == tg) break;
          __builtin_amdgcn_s_sleep(1);
        }
        float pv = __uint_as_float((unsigned)w);
        float cm = wave_max(pv);
        if (lane == 0) pmx[1][t & 1][wv] = cm;
        float q = 0.f;
        #pragma unroll
        for (int k = 0; k < 64; ++k)
          q = fmaf(rlane(pv, k), Areg[k >> 2][k & 3], q);
        prt[1][t & 1][wv][lane] = q;
        // prefetch next step's phase-0 (stores for tag t are ~in flight now)
        if (t + 1 < TT) {
          pf = AL(recbase(p64, g0, t) + wv * 64 + lane);
          if (wv == 0) xvn = clamp30(x[g0 * (TT * CC) + (t + 1) * CC + pdfj]);
        }
        __syncthreads();
        if (wv == 0) {
          float qq = 0.f;
          #pragma unroll
          for (int w8 = 0; w8 < 8; ++w8) qq += prt[1][t & 1][w8][lane];
          float m = pmx[1][t & 1][0];
          #pragma unroll
          for (int w8 = 1; w8 < 8; ++w8) m = fmaxf(m, pmx[1][t & 1][w8]);
          float lm = __logf(m);
          if (t < sl1) {
            pc1 = qq * __expf(xvp - SHIFTC - lm);
            sc1 += SHIFTC + lm;
          }
          AS(recbase(p64, g1, t) + j0 + lane, pk((unsigned)t, pc1));
          xvp = xvn;
        }
      }
    }

    if (wv == 0) {
      float e = __expf(lfj);
      float part0 = wave_sum(pc0 * e);
      float part1 = wave_sum(pc1 * e);
      if (lane == 0) {
        atomicAdd(wsf + WSF_DACC + g0, part0);
        atomicAdd(wsf + WSF_DACC + g1, part1);
        if (cb == 0) {
          wsf[WSF_DSCALE + g0] = sc0;
          wsf[WSF_DSCALE + g1] = sc1;
        }
      }
    }
  } else {
    // ---------------- NUM (per-batch A, S=64), single wave, pure VALU -------
    const int b = blockIdx.x - NDENWG;
    if (wv != 0) return;

    f4 Areg[16];
    {
      const float* Ap = nA + b * SN * SN + lane;
      #pragma unroll
      for (int i = 0; i < 64; ++i)
        Areg[i >> 2][i & 3] = __expf(Ap[i * SN]);
      #pragma unroll
      for (int r = 0; r < 16; ++r)
        asm volatile("" : "+v"(Areg[r]));
    }
    const int   pdfj = npdf[b * SN + lane];
    const float lfj  = nlf[b * SN + lane];
    const int   sl   = seqlens[b];
    float xv0 = clamp30(x[b * (TT * CC) + pdfj]);
    float pcur = __expf(nls[b * SN + lane] + xv0 - SHIFTC);
    float scale = SHIFTC;
    float xn = clamp30(x[b * (TT * CC) + CC + pdfj]);   // prefetch t=1

    for (int t = 1; t < TT; ++t) {
      float xv = xn;
      if (t + 1 < TT)
        xn = clamp30(x[b * (TT * CC) + (t + 1) * CC + pdfj]);
      float pold = pcur;
      float q = 0.f;
      #pragma unroll
      for (int i = 0; i < 64; ++i) {
        float pi = rlane(pold, i);
        q = fmaf(pi, Areg[i >> 2][i & 3], q);
      }
      float lm = __logf(wave_max(pold));
      if (t < sl) {
        pcur = q * __expf(xv - SHIFTC - lm);
        scale += SHIFTC + lm;
      }
    }
    float part = wave_sum(pcur * __expf(lfj));
    if (lane == 0) {
      wsf[WSF_NACC + b]   = part;
      wsf[WSF_NSCALE + b] = scale;
    }
  }
}

__global__ void fsm_final(const float* __restrict__ wsf, float* __restrict__ out) {
  const int tid = threadIdx.x;
  float v = 0.f;
  if (tid < 16)
    v = -(wsf[WSF_NSCALE + tid] + __logf(wsf[WSF_NACC + tid]));
  else if (tid < 32)
    v = (wsf[WSF_DSCALE + tid - 16] + __logf(wsf[WSF_DACC + tid - 16]));
  v = wave_sum(v);
  if (tid == 0) out[0] = v;  // loss = den_sum - num_sum
}

extern "C" void kernel_launch(void* const* d_in, const int* in_sizes, int n_in,
                              void* d_out, int out_size, void* d_ws, size_t ws_size,
                              hipStream_t stream) {
  const float* x    = (const float*)d_in[0];
  const int*   sql  = (const int*)d_in[1];
  const float* nA   = (const float*)d_in[2];
  const float* nls  = (const float*)d_in[3];
  const float* nlf  = (const float*)d_in[4];
  const int*   npdf = (const int*)d_in[5];
  const float* dA   = (const float*)d_in[6];
  const float* dls  = (const float*)d_in[7];
  const float* dlf  = (const float*)d_in[8];
  const int*   dpdf = (const int*)d_in[9];
  float* out = (float*)d_out;
  unsigned long long* p64 = (unsigned long long*)d_ws;
  float* wsf = (float*)d_ws;
  (void)in_sizes; (void)n_in; (void)out_size; (void)ws_size;

  // zero only the accumulators; tagged region tolerates stale tags (monotone)
  hipMemsetAsync((char*)d_ws + 131072, 0, 256, stream);
  fsm_fwd<<<NDENWG + BB, NTHR, 0, stream>>>(x, sql, nA, nls, nlf, npdf,
                                            dA, dls, dlf, dpdf, p64, wsf);
  fsm_final<<<1, 64, 0, stream>>>(wsf, out);
}

// Round 4
// 878.074 us; speedup vs baseline: 1.7427x; 1.7427x over previous
//
#include <hip/hip_runtime.h>
#include <math.h>

#define BB 16
#define TT 500
#define CC 2048
#define SN 64
#define SD 512
#define NGRP 16         // den groups (1 batch each)
#define NCB 8           // column blocks of 64 per group
#define NDEN 128        // 16 * 8
#define NTHR 512
#define SHIFTC 30.0f

// ws layout:
//   bytes [0, 131072): u64 pg[2][16][512] -- (tag<<32)|float_bits, [buf][group/batch][state]
//   float index 32768+: DACC[16], DSCALE[16], NACC[16], NSCALE[16]
#define WSF_DACC   32768
#define WSF_DSCALE 32784
#define WSF_NACC   32800
#define WSF_NSCALE 32816

#define AL(p) __hip_atomic_load((p), __ATOMIC_RELAXED, __HIP_MEMORY_SCOPE_AGENT)
#define AS(p, v) __hip_atomic_store((p), (v), __ATOMIC_RELAXED, __HIP_MEMORY_SCOPE_AGENT)

typedef float f4 __attribute__((ext_vector_type(4)));

__device__ __forceinline__ float wave_max(float v) {
  #pragma unroll
  for (int off = 32; off > 0; off >>= 1) v = fmaxf(v, __shfl_xor(v, off, 64));
  return v;
}
__device__ __forceinline__ float wave_sum(float v) {
  #pragma unroll
  for (int off = 32; off > 0; off >>= 1) v += __shfl_xor(v, off, 64);
  return v;
}
__device__ __forceinline__ unsigned long long pk(unsigned tag, float v) {
  return ((unsigned long long)tag << 32) | (unsigned long long)__float_as_uint(v);
}
__device__ __forceinline__ float clamp30(float v) {
  return fminf(fmaxf(v, -30.f), 30.f);
}
__device__ __forceinline__ float rlane(float v, int k) {
  return __uint_as_float(__builtin_amdgcn_readlane(__float_as_uint(v), k));
}

// Barrier that orders LDS only. __syncthreads() emits s_waitcnt vmcnt(0)
// before s_barrier, draining in-flight global loads (our poll/emission
// prefetches!) -- this was serializing the prefetch latency into every step.
// LDS producer/consumer ordering needs only lgkmcnt + s_barrier.
__device__ __forceinline__ void barrier_lds_only() {
  asm volatile("s_waitcnt lgkmcnt(0)" ::: "memory");
  __builtin_amdgcn_s_barrier();
  asm volatile("" ::: "memory");
}

__global__ __launch_bounds__(NTHR, 1) void fsm_fwd(
    const float* __restrict__ x, const int* __restrict__ seqlens,
    const float* __restrict__ nA, const float* __restrict__ nls,
    const float* __restrict__ nlf, const int* __restrict__ npdf,
    const float* __restrict__ dA, const float* __restrict__ dls,
    const float* __restrict__ dlf, const int* __restrict__ dpdf,
    unsigned long long* __restrict__ p64, float* __restrict__ wsf)
{
  __shared__ float prt[2][8 * 64];   // double-buffered per-wave partial q
  __shared__ float pmx[2][8];        // double-buffered per-wave chunk maxes
  const int tid = threadIdx.x;
  const int lane = tid & 63, wv = tid >> 6;

  if (blockIdx.x < NDEN) {
    // ---------------- DEN (shared A, S=512), 1 batch per group --------------
    // g = bid & 15 keeps all 8 column-block WGs of a group at the same
    // (bid % 8) => same XCD under round-robin dispatch => L2-local exchange.
    const int g  = blockIdx.x & 15;     // group == batch
    const int cb = blockIdx.x >> 4;     // column block (0..7)
    const int j0 = cb * 64;

    // A in registers: lane holds exp(A[i0+k][j0+lane]) for its wave's i-window
    f4 Areg[16];
    {
      const float* Ap = dA + (wv * 64) * SD + j0 + lane;
      #pragma unroll
      for (int k = 0; k < 64; ++k)
        Areg[k >> 2][k & 3] = __expf(Ap[k * SD]);
      #pragma unroll
      for (int r = 0; r < 16; ++r)
        asm volatile("" : "+v"(Areg[r]));   // keep resident across the loop
    }

    unsigned long long* gb0 = p64 + (size_t)g * SD;              // buf 0
    unsigned long long* gb1 = p64 + (size_t)(NGRP + g) * SD;     // buf 1

    // wave 0 owns the epilogue state for this WG's 64 columns
    int pdfj = 0, sl = 0; float lfj = 0.f, pcur = 0.f, scale = SHIFTC;
    float xc = 0.f;                       // emission for current step t
    if (wv == 0) {
      pdfj = dpdf[j0 + lane];
      lfj  = dlf[j0 + lane];
      sl   = seqlens[g];
      float xv = clamp30(x[g * (TT * CC) + pdfj]);
      pcur = __expf(dls[j0 + lane] + xv - SHIFTC);
      AS(gb0 + j0 + lane, pk(0u, pcur));
      // emission prefetch for t=1 (in flight across the first poll)
      xc = clamp30(x[g * (TT * CC) + CC + pdfj]);
    }

    for (int t = 1; t < TT; ++t) {
      unsigned long long* gin  = (t & 1) ? gb0 : gb1;
      unsigned long long* gout = (t & 1) ? gb1 : gb0;

      // poll own chunk: wave wv consumes producer WG cb==wv's 64 words
      const unsigned tg = (unsigned)(t - 1);
      unsigned long long* pa = gin + wv * 64 + lane;
      unsigned long long w;
      for (;;) {
        w = AL(pa);
        if ((unsigned)(w >> 32) == tg) break;
        __builtin_amdgcn_s_sleep(1);
      }
      float pv = __uint_as_float((unsigned)w);

      // chunk max for the lagged renormalizer
      float cm = wave_max(pv);
      if (lane == 0) pmx[t & 1][wv] = cm;

      // matvec over own i-window: broadcast p via v_readlane (pure VALU)
      float q = 0.f;
      #pragma unroll
      for (int k = 0; k < 64; ++k) {
        float pk_ = rlane(pv, k);
        q = fmaf(pk_, Areg[k >> 2][k & 3], q);
      }
      prt[t & 1][wv * 64 + lane] = q;

      barrier_lds_only();   // LDS-ordering only: does NOT drain global loads

      if (wv == 0) {
        const float* pb = prt[t & 1];
        float qq = 0.f;
        #pragma unroll
        for (int w8 = 0; w8 < 8; ++w8) qq += pb[w8 * 64 + lane];
        float m = pmx[t & 1][0];
        #pragma unroll
        for (int w8 = 1; w8 < 8; ++w8) m = fmaxf(m, pmx[t & 1][w8]);
        float lm = __logf(m);
        if (t < sl) {
          pcur = qq * __expf(xc - SHIFTC - lm);
          scale += SHIFTC + lm;
        }
        AS(gout + j0 + lane, pk((unsigned)t, pcur));  // coalesced 512B burst
        // emission prefetch for t+1: issued AFTER the store, ~one full
        // step (~C cycles) of slack before its use -- never stalls.
        if (t + 1 < TT)
          xc = clamp30(x[g * (TT * CC) + (t + 1) * CC + pdfj]);
      }
      // waves 1..7 go straight to polling t+1 (prt/pmx double-buffered)
    }
    if (wv == 0) {
      float part = wave_sum(pcur * __expf(lfj));
      if (lane == 0) {
        atomicAdd(wsf + WSF_DACC + g, part);
        if (cb == 0) wsf[WSF_DSCALE + g] = scale;
      }
    }
  } else {
    // ---------------- NUM (per-batch A, S=64), single wave, pure VALU -------
    const int b = blockIdx.x - NDEN;
    if (wv != 0) return;

    f4 Areg[16];   // lane holds exp(nA[i][lane]) for all i
    {
      const float* Ap = nA + b * SN * SN + lane;
      #pragma unroll
      for (int i = 0; i < 64; ++i)
        Areg[i >> 2][i & 3] = __expf(Ap[i * SN]);
      #pragma unroll
      for (int r = 0; r < 16; ++r)
        asm volatile("" : "+v"(Areg[r]));
    }
    const int   pdfj = npdf[b * SN + lane];
    const float lfj  = nlf[b * SN + lane];
    const int   sl   = seqlens[b];
    float xv0 = clamp30(x[b * (TT * CC) + pdfj]);
    float pcur = __expf(nls[b * SN + lane] + xv0 - SHIFTC);
    float scale = SHIFTC;
    float xn = clamp30(x[b * (TT * CC) + CC + pdfj]);   // prefetch t=1

    for (int t = 1; t < TT; ++t) {
      float xv = xn;
      if (t + 1 < TT)
        xn = clamp30(x[b * (TT * CC) + (t + 1) * CC + pdfj]);
      float pold = pcur;
      float q = 0.f;
      #pragma unroll
      for (int i = 0; i < 64; ++i) {
        float pi = rlane(pold, i);
        q = fmaf(pi, Areg[i >> 2][i & 3], q);
      }
      float lm = __logf(wave_max(pold));
      if (t < sl) {
        pcur = q * __expf(xv - SHIFTC - lm);
        scale += SHIFTC + lm;
      }
    }
    float part = wave_sum(pcur * __expf(lfj));
    if (lane == 0) {
      wsf[WSF_NACC + b]   = part;
      wsf[WSF_NSCALE + b] = scale;
    }
  }
}

__global__ void fsm_final(const float* __restrict__ wsf, float* __restrict__ out) {
  const int tid = threadIdx.x;
  float v = 0.f;
  if (tid < 16)
    v = -(wsf[WSF_NSCALE + tid] + __logf(wsf[WSF_NACC + tid]));
  else if (tid < 32)
    v = (wsf[WSF_DSCALE + tid - 16] + __logf(wsf[WSF_DACC + tid - 16]));
  v = wave_sum(v);
  if (tid == 0) out[0] = v;  // loss = den_sum - num_sum
}

extern "C" void kernel_launch(void* const* d_in, const int* in_sizes, int n_in,
                              void* d_out, int out_size, void* d_ws, size_t ws_size,
                              hipStream_t stream) {
  const float* x    = (const float*)d_in[0];
  const int*   sql  = (const int*)d_in[1];
  const float* nA   = (const float*)d_in[2];
  const float* nls  = (const float*)d_in[3];
  const float* nlf  = (const float*)d_in[4];
  const int*   npdf = (const int*)d_in[5];
  const float* dA   = (const float*)d_in[6];
  const float* dls  = (const float*)d_in[7];
  const float* dlf  = (const float*)d_in[8];
  const int*   dpdf = (const int*)d_in[9];
  float* out = (float*)d_out;
  unsigned long long* p64 = (unsigned long long*)d_ws;
  float* wsf = (float*)d_ws;
  (void)in_sizes; (void)n_in; (void)out_size; (void)ws_size;

  // zero only the accumulators; tagged region relies on 0xAA poison != any tag
  hipMemsetAsync((char*)d_ws + 131072, 0, 256, stream);
  fsm_fwd<<<NDEN + BB, NTHR, 0, stream>>>(x, sql, nA, nls, nlf, npdf,
                                          dA, dls, dlf, dpdf, p64, wsf);
  fsm_final<<<1, 64, 0, stream>>>(wsf, out);
}